// Round 1
// baseline (230.864 us; speedup 1.0000x reference)
//
#include <hip/hip_runtime.h>
#include <math.h>

#define B_N 131072
#define G_N 8
#define GS_N 8
#define K_N 8
#define O_N 16
#define TOT_N 128
#define R_N 10
#define FIN_N 20

// ---------------- workspace layout (float offsets) ----------------
// [0, 2048)      stat1: 8 stripes x (sum[128], sumsq[128])
// [2048, 3328)   Mt[64][20]  (BN1+fp_W+proj_W folded, transposed)
// [3328, 3348)   C[20]
// [3352, 3672)   stat2: 8 stripes x (sum[20], sumsq[20])
// [3672, 3712)   sc2: scale[20], shift[20]
// [3712, 4112)   nh: nhu[200], nhl[200]
// [4224, ...)    z_pre column-major [20][B]   (optional, if ws big enough)
#define WS_STAT1 0
#define WS_MT    2048
#define WS_C     3328
#define WS_STAT2 3352
#define WS_SC2   3672
#define WS_NH    3712
#define WS_Z     4224

__global__ __launch_bounds__(256) void k_init(float* __restrict__ ws) {
    int i = blockIdx.x * 256 + threadIdx.x;
    if (i < 4224) ws[i] = 0.0f;
}

// ---------------- pass 1: BN1 statistics over proj ----------------
// mapping: g = tid&7 (one group per thread), rl = tid>>3 (32 rows / block / iter)
__global__ __launch_bounds__(256) void k_proj_stats(
    const float* __restrict__ x, const float* __restrict__ cen,
    const float* __restrict__ lw, const float* __restrict__ rw,
    const float* __restrict__ linw, const float* __restrict__ Wp,
    const float* __restrict__ pb, float* __restrict__ stat1)
{
    __shared__ __align__(16) float sWp[8 * 132];   // padded by 4 floats per group
    __shared__ __align__(16) float red[256 * 16];

    const int tid = threadIdx.x;
    for (int i = tid; i < 1024; i += 256) {
        int g = i >> 7;
        sWp[i + 4 * g] = Wp[i];
    }
    __syncthreads();

    const int g = tid & 7;
    const int rl = tid >> 3;

    float c_[8], nh_[8], w_[8];
#pragma unroll
    for (int k = 0; k < 8; ++k) {
        c_[k] = cen[g * 8 + k];
        float s = expf(lw[g * 8 + k]) + 1e-6f;
        nh_[k] = -0.5f / (s * s);
        w_[k] = rw[g * 8 + k];
    }
    const float lin = linw[g];
    float pb_[16];
#pragma unroll
    for (int o = 0; o < 16; ++o) pb_[o] = pb[g * 16 + o];

    float sum[16], sq[16];
#pragma unroll
    for (int o = 0; o < 16; ++o) { sum[o] = 0.0f; sq[o] = 0.0f; }

    const float* sWpg = sWp + g * 132;
    for (int row = blockIdx.x * 32 + rl; row < B_N; row += gridDim.x * 32) {
        const float* xr = x + (size_t)row * 64 + g * 8;
        float4 v0 = *(const float4*)(xr);
        float4 v1 = *(const float4*)(xr + 4);
        float xv[8] = {v0.x, v0.y, v0.z, v0.w, v1.x, v1.y, v1.z, v1.w};
        float act[8];
#pragma unroll
        for (int f = 0; f < 8; ++f) {
            float v = xv[f];
            float a = lin * v;
#pragma unroll
            for (int k = 0; k < 8; ++k) {
                float d = v - c_[k];
                a += w_[k] * __expf(d * d * nh_[k]);
            }
            act[f] = a;
        }
#pragma unroll
        for (int o = 0; o < 16; ++o) {
            const float4* wp4 = (const float4*)(sWpg + o * 8);
            float4 wa = wp4[0], wb = wp4[1];
            float p = pb_[o]
                + act[0] * wa.x + act[1] * wa.y + act[2] * wa.z + act[3] * wa.w
                + act[4] * wb.x + act[5] * wb.y + act[6] * wb.z + act[7] * wb.w;
            sum[o] += p;
            sq[o]  += p * p;
        }
    }

    // block tree-reduction (pairs always share the same g since s >= 8)
    for (int pass = 0; pass < 2; ++pass) {
        float* vals = pass ? sq : sum;
        __syncthreads();
#pragma unroll
        for (int o = 0; o < 16; ++o) red[tid * 16 + o] = vals[o];
        __syncthreads();
        for (int s = 128; s >= 8; s >>= 1) {
            if (tid < s) {
#pragma unroll
                for (int o = 0; o < 16; ++o)
                    red[tid * 16 + o] += red[(tid + s) * 16 + o];
            }
            __syncthreads();
        }
        if (tid < 8) {
            float* dst = stat1 + (blockIdx.x & 7) * 256 + pass * 128 + tid * 16;
#pragma unroll
            for (int o = 0; o < 16; ++o) atomicAdd(&dst[o], red[tid * 16 + o]);
        }
    }
}

// ---------------- build folded matrix M, bias C, fuzzy tables ----------------
__global__ __launch_bounds__(256) void k_build(
    const float* __restrict__ stat1, const float* __restrict__ fpW,
    const float* __restrict__ fpb, const float* __restrict__ g1,
    const float* __restrict__ b1, const float* __restrict__ Wp,
    const float* __restrict__ pb, const float* __restrict__ lsu,
    const float* __restrict__ lsl,
    float* __restrict__ Mt, float* __restrict__ Cc, float* __restrict__ nh)
{
    __shared__ float a_[128], bb_[128];
    const int t = threadIdx.x;
    if (t < 128) {
        float s = 0.0f, q = 0.0f;
        for (int st = 0; st < 8; ++st) {
            s += stat1[st * 256 + t];
            q += stat1[st * 256 + 128 + t];
        }
        float mu = s * (1.0f / B_N);
        float var = q * (1.0f / B_N) - mu * mu;
        float a = g1[t] * rsqrtf(var + 1e-5f);
        a_[t] = a;
        bb_[t] = b1[t] - mu * a;
    }
    __syncthreads();
    // Mt[gf][j] = sum_o fp_W[j, g*16+o] * a[g*16+o] * proj_W[g,o,f]
    for (int i = t; i < 1280; i += 256) {
        int gf = i / 20, j = i % 20;
        int g = gf >> 3, f = gf & 7;
        float m = 0.0f;
        for (int o = 0; o < 16; ++o) {
            int c = g * 16 + o;
            m += fpW[j * 128 + c] * a_[c] * Wp[c * 8 + f];
        }
        Mt[i] = m;
    }
    if (t < 20) {
        float cj = fpb[t];
        for (int c = 0; c < 128; ++c)
            cj += fpW[t * 128 + c] * (a_[c] * pb[c] + bb_[c]);
        Cc[t] = cj;
    }
    for (int i = t; i < 200; i += 256) {
        float su = expf(lsu[i]) + 1e-6f;
        float sl = fminf(expf(lsl[i]) + 1e-6f, 0.9f * su);
        nh[i] = -0.5f / (su * su);
        nh[200 + i] = -0.5f / (sl * sl);
    }
}

// ---------------- shared device helper: x row -> z_pre[20] ----------------
__device__ __forceinline__ void zpre_row(
    const float* __restrict__ xr,
    const float4* __restrict__ sRbf,   // [64]: (centre, weight, -0.5/sigma^2, _)
    const float* __restrict__ sLin,    // [8]
    const float* __restrict__ sMt,     // [64][20]
    const float* __restrict__ sC,      // [20]
    float zp[20])
{
#pragma unroll
    for (int j = 0; j < 20; ++j) zp[j] = sC[j];
#pragma unroll 1
    for (int g = 0; g < 8; ++g) {
        float4 v0 = *(const float4*)(xr + g * 8);
        float4 v1 = *(const float4*)(xr + g * 8 + 4);
        float xv[8] = {v0.x, v0.y, v0.z, v0.w, v1.x, v1.y, v1.z, v1.w};
        float act[8];
        float lin = sLin[g];
#pragma unroll
        for (int f = 0; f < 8; ++f) act[f] = lin * xv[f];
#pragma unroll 1
        for (int k = 0; k < 8; ++k) {
            float4 p = sRbf[g * 8 + k];
#pragma unroll
            for (int f = 0; f < 8; ++f) {
                float d = xv[f] - p.x;
                act[f] += p.y * __expf(d * d * p.z);
            }
        }
#pragma unroll 1
        for (int f = 0; f < 8; ++f) {
            float a = act[f];
            const float* m = sMt + (g * 8 + f) * 20;
#pragma unroll
            for (int j = 0; j < 20; ++j) zp[j] += a * m[j];
        }
    }
}

__device__ __forceinline__ void load_rbf_lds(
    const float* cen, const float* lw, const float* rw, const float* linw,
    const float* Mt, const float* Cc,
    float4* sRbf, float* sLin, float* sMt, float* sC, int t)
{
    if (t < 64) {
        float s = expf(lw[t]) + 1e-6f;
        sRbf[t] = make_float4(cen[t], rw[t], -0.5f / (s * s), 0.0f);
    }
    if (t < 8)  sLin[t] = linw[t];
    if (t < 20) sC[t] = Cc[t];
    for (int i = t; i < 1280; i += 256) sMt[i] = Mt[i];
}

// ---------------- pass 2: z_pre + BN2 statistics ----------------
__global__ __launch_bounds__(256) void k_zpre_stats(
    const float* __restrict__ x, const float* __restrict__ cen,
    const float* __restrict__ lw, const float* __restrict__ rw,
    const float* __restrict__ linw, const float* __restrict__ Mt,
    const float* __restrict__ Cc, float* __restrict__ zout,
    float* __restrict__ stat2, int store)
{
    __shared__ __align__(16) float4 sRbf[64];
    __shared__ float sLin[8], sC[20];
    __shared__ __align__(16) float sMt[1280];
    __shared__ float sRed[4][40];

    const int t = threadIdx.x;
    load_rbf_lds(cen, lw, rw, linw, Mt, Cc, sRbf, sLin, sMt, sC, t);
    __syncthreads();

    const int row = blockIdx.x * 256 + t;
    float zp[20];
    zpre_row(x + (size_t)row * 64, sRbf, sLin, sMt, sC, zp);

    if (store) {
#pragma unroll
        for (int j = 0; j < 20; ++j) zout[(size_t)j * B_N + row] = zp[j];
    }

    // BN2 partial stats: wave shuffle reduce -> LDS -> striped atomics
    float s_[20], q_[20];
#pragma unroll
    for (int j = 0; j < 20; ++j) { s_[j] = zp[j]; q_[j] = zp[j] * zp[j]; }
#pragma unroll
    for (int off = 32; off >= 1; off >>= 1) {
#pragma unroll
        for (int j = 0; j < 20; ++j) {
            s_[j] += __shfl_down(s_[j], off, 64);
            q_[j] += __shfl_down(q_[j], off, 64);
        }
    }
    const int wave = t >> 6, lane = t & 63;
    if (lane == 0) {
#pragma unroll
        for (int j = 0; j < 20; ++j) {
            sRed[wave][j] = s_[j];
            sRed[wave][20 + j] = q_[j];
        }
    }
    __syncthreads();
    if (t < 40) {
        float v = sRed[0][t] + sRed[1][t] + sRed[2][t] + sRed[3][t];
        atomicAdd(&stat2[(blockIdx.x & 7) * 40 + t], v);
    }
}

// ---------------- BN2 finalize ----------------
__global__ __launch_bounds__(64) void k_bn2(
    const float* __restrict__ stat2, const float* __restrict__ g2,
    const float* __restrict__ b2, float* __restrict__ sc2)
{
    const int t = threadIdx.x;
    if (t < 20) {
        float s = 0.0f, q = 0.0f;
        for (int st = 0; st < 8; ++st) {
            s += stat2[st * 40 + t];
            q += stat2[st * 40 + 20 + t];
        }
        float mu = s * (1.0f / B_N);
        float var = q * (1.0f / B_N) - mu * mu;
        float sc = g2[t] * rsqrtf(var + 1e-5f);
        sc2[t] = sc;
        sc2[20 + t] = b2[t] - mu * sc;
    }
}

__device__ __forceinline__ float gelu_exact(float v) {
    return 0.5f * v * (1.0f + erff(v * 0.70710678118654752440f));
}

__device__ __forceinline__ float fuzzy_head(
    const float z[20], const float4* sFz, const float* sHW, float hb)
{
    float acc = hb;
#pragma unroll 1
    for (int r = 0; r < 10; ++r) {
        float u = 0.0f, l = 0.0f;
#pragma unroll
        for (int j = 0; j < 20; ++j) {
            float4 p = sFz[r * 20 + j];   // (centre, nhu, nhl, _)
            float d = z[j] - p.x;
            float dd = d * d;
            u += __expf(dd * p.y);
            l += __expf(dd * p.z);
        }
        acc += sHW[r] * 0.025f * (u + l);   // 0.5 * mean(20) folded: /40
    }
    return acc;
}

// ---------------- pass 3 (variant A): load z_pre from ws ----------------
__global__ __launch_bounds__(256) void k_out_load(
    const float* __restrict__ zin, const float* __restrict__ sc2,
    const float* __restrict__ nh, const float* __restrict__ fzc,
    const float* __restrict__ hW, const float* __restrict__ hb,
    float* __restrict__ out)
{
    __shared__ float sSc[20], sSh[20], sHW[10];
    __shared__ __align__(16) float4 sFz[200];
    const int t = threadIdx.x;
    if (t < 20) { sSc[t] = sc2[t]; sSh[t] = sc2[20 + t]; }
    if (t < 10) sHW[t] = hW[t];
    for (int i = t; i < 200; i += 256)
        sFz[i] = make_float4(fzc[i], nh[i], nh[200 + i], 0.0f);
    __syncthreads();

    const int row = blockIdx.x * 256 + t;
    float z[20];
#pragma unroll
    for (int j = 0; j < 20; ++j) {
        float zp = zin[(size_t)j * B_N + row];
        z[j] = gelu_exact(sSc[j] * zp + sSh[j]);
    }
    out[row] = fuzzy_head(z, sFz, sHW, hb[0]);
}

// ---------------- pass 3 (variant B): recompute z_pre from x ----------------
__global__ __launch_bounds__(256) void k_out_rec(
    const float* __restrict__ x, const float* __restrict__ cen,
    const float* __restrict__ lw, const float* __restrict__ rw,
    const float* __restrict__ linw, const float* __restrict__ Mt,
    const float* __restrict__ Cc, const float* __restrict__ sc2,
    const float* __restrict__ nh, const float* __restrict__ fzc,
    const float* __restrict__ hW, const float* __restrict__ hb,
    float* __restrict__ out)
{
    __shared__ __align__(16) float4 sRbf[64];
    __shared__ float sLin[8], sC[20];
    __shared__ __align__(16) float sMt[1280];
    __shared__ float sSc[20], sSh[20], sHW[10];
    __shared__ __align__(16) float4 sFz[200];

    const int t = threadIdx.x;
    load_rbf_lds(cen, lw, rw, linw, Mt, Cc, sRbf, sLin, sMt, sC, t);
    if (t < 20) { sSc[t] = sc2[t]; sSh[t] = sc2[20 + t]; }
    if (t < 10) sHW[t] = hW[t];
    for (int i = t; i < 200; i += 256)
        sFz[i] = make_float4(fzc[i], nh[i], nh[200 + i], 0.0f);
    __syncthreads();

    const int row = blockIdx.x * 256 + t;
    float zp[20];
    zpre_row(x + (size_t)row * 64, sRbf, sLin, sMt, sC, zp);
    float z[20];
#pragma unroll
    for (int j = 0; j < 20; ++j)
        z[j] = gelu_exact(sSc[j] * zp[j] + sSh[j]);
    out[row] = fuzzy_head(z, sFz, sHW, hb[0]);
}

// ---------------- launcher ----------------
extern "C" void kernel_launch(void* const* d_in, const int* in_sizes, int n_in,
                              void* d_out, int out_size, void* d_ws, size_t ws_size,
                              hipStream_t stream) {
    const float* x    = (const float*)d_in[0];
    const float* cen  = (const float*)d_in[1];
    const float* lw   = (const float*)d_in[2];
    const float* rw   = (const float*)d_in[3];
    const float* linw = (const float*)d_in[4];
    const float* Wp   = (const float*)d_in[5];
    const float* pb   = (const float*)d_in[6];
    const float* g1   = (const float*)d_in[7];
    const float* b1   = (const float*)d_in[8];
    const float* fpW  = (const float*)d_in[9];
    const float* fpb  = (const float*)d_in[10];
    const float* g2   = (const float*)d_in[11];
    const float* b2   = (const float*)d_in[12];
    const float* fzc  = (const float*)d_in[13];
    const float* lsu  = (const float*)d_in[14];
    const float* lsl  = (const float*)d_in[15];
    const float* hW   = (const float*)d_in[16];
    const float* hb   = (const float*)d_in[17];

    float* ws    = (float*)d_ws;
    float* stat1 = ws + WS_STAT1;
    float* Mt    = ws + WS_MT;
    float* Cc    = ws + WS_C;
    float* stat2 = ws + WS_STAT2;
    float* sc2   = ws + WS_SC2;
    float* nh    = ws + WS_NH;
    float* zbuf  = ws + WS_Z;
    float* outp  = (float*)d_out;

    const size_t need = ((size_t)WS_Z + (size_t)20 * B_N) * sizeof(float);
    const int store = (ws_size >= need) ? 1 : 0;

    k_init<<<17, 256, 0, stream>>>(ws);
    k_proj_stats<<<1024, 256, 0, stream>>>(x, cen, lw, rw, linw, Wp, pb, stat1);
    k_build<<<1, 256, 0, stream>>>(stat1, fpW, fpb, g1, b1, Wp, pb, lsu, lsl,
                                   Mt, Cc, nh);
    k_zpre_stats<<<512, 256, 0, stream>>>(x, cen, lw, rw, linw, Mt, Cc,
                                          store ? zbuf : nullptr, stat2, store);
    k_bn2<<<1, 64, 0, stream>>>(stat2, g2, b2, sc2);
    if (store) {
        k_out_load<<<512, 256, 0, stream>>>(zbuf, sc2, nh, fzc, hW, hb, outp);
    } else {
        k_out_rec<<<512, 256, 0, stream>>>(x, cen, lw, rw, linw, Mt, Cc,
                                           sc2, nh, fzc, hW, hb, outp);
    }
}

// Round 2
// 182.338 us; speedup vs baseline: 1.2661x; 1.2661x over previous
//
#include <hip/hip_runtime.h>
#include <math.h>

#define B_N 131072
#define R_N 10
#define FIN_N 20

// ---------------- workspace layout (float offsets) ----------------
// stat1: 64 stripes x 352 (per-group act moments: 8 sum + 36 second-moment)
#define WS_STAT1 0
#define ST1_SZ   (64 * 352)          // 22528
#define WS_MT    22528               // Mt[64][20]
#define WS_C     23808               // C[20]
#define WS_STAT2 23828               // 64 stripes x 40
#define WS_NH    26388               // nhu[200], nhl[200]
#define WS_Z     26816               // z_pre column-major [20][B]

// ---------------- pass 1: act moments (for BN1 stats) ----------------
// thread -> (row-slot rl = tid>>3, group g = tid&7); 1024 blocks, 4 row iters
__global__ __launch_bounds__(256) void k_act_moments(
    const float* __restrict__ x, const float* __restrict__ cen,
    const float* __restrict__ lw, const float* __restrict__ rw,
    const float* __restrict__ linw, float* __restrict__ stat1)
{
    __shared__ float sAcc[4][8][44];

    const int t = threadIdx.x;
    const int g = t & 7;
    const int rl = t >> 3;

    float c_[8], nh_[8], w_[8];
#pragma unroll
    for (int k = 0; k < 8; ++k) {
        c_[k] = cen[g * 8 + k];
        float s = expf(lw[g * 8 + k]) + 1e-6f;
        nh_[k] = -0.5f / (s * s);
        w_[k] = rw[g * 8 + k];
    }
    const float lin = linw[g];

    float sumA[8], P[36];
#pragma unroll
    for (int f = 0; f < 8; ++f) sumA[f] = 0.0f;
#pragma unroll
    for (int i = 0; i < 36; ++i) P[i] = 0.0f;

    for (int row = blockIdx.x * 32 + rl; row < B_N; row += gridDim.x * 32) {
        const float* xr = x + (size_t)row * 64 + g * 8;
        float4 v0 = *(const float4*)(xr);
        float4 v1 = *(const float4*)(xr + 4);
        float xv[8] = {v0.x, v0.y, v0.z, v0.w, v1.x, v1.y, v1.z, v1.w};
        float act[8];
#pragma unroll
        for (int f = 0; f < 8; ++f) {
            float v = xv[f];
            float a = lin * v;
#pragma unroll
            for (int k = 0; k < 8; ++k) {
                float d = v - c_[k];
                a += w_[k] * __expf(d * d * nh_[k]);
            }
            act[f] = a;
        }
        int idx = 0;
#pragma unroll
        for (int f = 0; f < 8; ++f) {
            sumA[f] += act[f];
#pragma unroll
            for (int f2 = 0; f2 <= f; ++f2) { P[idx] += act[f] * act[f2]; ++idx; }
        }
    }

    // wave shuffle reduce over lanes sharing the same g (offsets 32,16,8)
#pragma unroll
    for (int off = 32; off >= 8; off >>= 1) {
#pragma unroll
        for (int f = 0; f < 8; ++f) sumA[f] += __shfl_down(sumA[f], off, 64);
#pragma unroll
        for (int i = 0; i < 36; ++i) P[i] += __shfl_down(P[i], off, 64);
    }
    const int wave = t >> 6, lane = t & 63;
    if (lane < 8) {   // lane == g here
        float* dst = &sAcc[wave][lane][0];
#pragma unroll
        for (int f = 0; f < 8; ++f) dst[f] = sumA[f];
#pragma unroll
        for (int i = 0; i < 36; ++i) dst[8 + i] = P[i];
    }
    __syncthreads();
    for (int i = t; i < 352; i += 256) {
        int gg = i / 44, v = i % 44;
        float s = sAcc[0][gg][v] + sAcc[1][gg][v] + sAcc[2][gg][v] + sAcc[3][gg][v];
        atomicAdd(&stat1[(blockIdx.x & 63) * 352 + i], s);
    }
}

// ---------------- build: BN1 from moments, fold M/C, fuzzy tables ----------------
__global__ __launch_bounds__(256) void k_build(
    const float* __restrict__ stat1, const float* __restrict__ fpW,
    const float* __restrict__ fpb, const float* __restrict__ g1,
    const float* __restrict__ b1, const float* __restrict__ Wp,
    const float* __restrict__ pb, const float* __restrict__ lsu,
    const float* __restrict__ lsl,
    float* __restrict__ Mt, float* __restrict__ Cc, float* __restrict__ nh,
    float* __restrict__ stat2)
{
    __shared__ float Am[8][8];     // E[act]
    __shared__ float Sg[8][36];    // E[act act^T] upper-tri (f2<=f)
    __shared__ float a_[128], bb_[128];
    const int t = threadIdx.x;

    for (int i = t; i < 352; i += 256) {
        float s = 0.0f;
        for (int st = 0; st < 64; ++st) s += stat1[st * 352 + i];
        float m = s * (1.0f / B_N);
        int g = i / 44, v = i % 44;
        if (v < 8) Am[g][v] = m; else Sg[g][v - 8] = m;
    }
    __syncthreads();

    if (t < 128) {
        const int g = t >> 4;
        float wv[8];
#pragma unroll
        for (int f = 0; f < 8; ++f) wv[f] = Wp[t * 8 + f];
        float dot = 0.0f;
#pragma unroll
        for (int f = 0; f < 8; ++f) dot += wv[f] * Am[g][f];
        const float pbv = pb[t];
        const float mu = pbv + dot;
        float e2 = pbv * pbv + 2.0f * pbv * dot;
        int idx = 0;
#pragma unroll
        for (int f = 0; f < 8; ++f)
#pragma unroll
            for (int f2 = 0; f2 <= f; ++f2) {
                float c2 = (f2 == f) ? 1.0f : 2.0f;
                e2 += c2 * wv[f] * wv[f2] * Sg[g][idx]; ++idx;
            }
        const float var = e2 - mu * mu;
        const float a = g1[t] * rsqrtf(var + 1e-5f);
        a_[t] = a;
        bb_[t] = b1[t] - mu * a;
    }
    __syncthreads();

    // Mt[gf][j] = sum_o fpW[j, g*16+o] * a[g*16+o] * Wp[g,o,f]
    for (int i = t; i < 1280; i += 256) {
        int gf = i / 20, j = i % 20;
        int g = gf >> 3, f = gf & 7;
        float m = 0.0f;
        for (int o = 0; o < 16; ++o) {
            int c = g * 16 + o;
            m += fpW[j * 128 + c] * a_[c] * Wp[c * 8 + f];
        }
        Mt[i] = m;
    }
    if (t < 20) {
        float cj = fpb[t];
        for (int c = 0; c < 128; ++c)
            cj += fpW[t * 128 + c] * (a_[c] * pb[c] + bb_[c]);
        Cc[t] = cj;
    }
    for (int i = t; i < 200; i += 256) {
        float su = expf(lsu[i]) + 1e-6f;
        float sl = fminf(expf(lsl[i]) + 1e-6f, 0.9f * su);
        nh[i] = -0.5f / (su * su);
        nh[200 + i] = -0.5f / (sl * sl);
    }
    for (int i = t; i < 2560; i += 256) stat2[i] = 0.0f;   // zero stat2 stripes
}

// ---------------- shared helper: x row -> z_pre[20] ----------------
__device__ __forceinline__ void zpre_row(
    const float* __restrict__ xr,
    const float4* __restrict__ sRbf,   // [64]: (centre, weight, -0.5/sigma^2, _)
    const float* __restrict__ sLin,    // [8]
    const float* __restrict__ sMt,     // [64][20]
    const float* __restrict__ sC,      // [20]
    float zp[20])
{
#pragma unroll
    for (int j = 0; j < 20; ++j) zp[j] = sC[j];
#pragma unroll 1
    for (int g = 0; g < 8; ++g) {
        float4 v0 = *(const float4*)(xr + g * 8);
        float4 v1 = *(const float4*)(xr + g * 8 + 4);
        float xv[8] = {v0.x, v0.y, v0.z, v0.w, v1.x, v1.y, v1.z, v1.w};
        float act[8];
        float lin = sLin[g];
#pragma unroll
        for (int f = 0; f < 8; ++f) act[f] = lin * xv[f];
#pragma unroll 1
        for (int k = 0; k < 8; ++k) {
            float4 p = sRbf[g * 8 + k];
#pragma unroll
            for (int f = 0; f < 8; ++f) {
                float d = xv[f] - p.x;
                act[f] += p.y * __expf(d * d * p.z);
            }
        }
#pragma unroll 1
        for (int f = 0; f < 8; ++f) {
            float a = act[f];
            const float4* m4 = (const float4*)(sMt + (g * 8 + f) * 20);
            float4 ma = m4[0], mb = m4[1], mc = m4[2], md = m4[3], me = m4[4];
            zp[0] += a * ma.x; zp[1] += a * ma.y; zp[2] += a * ma.z; zp[3] += a * ma.w;
            zp[4] += a * mb.x; zp[5] += a * mb.y; zp[6] += a * mb.z; zp[7] += a * mb.w;
            zp[8] += a * mc.x; zp[9] += a * mc.y; zp[10] += a * mc.z; zp[11] += a * mc.w;
            zp[12] += a * md.x; zp[13] += a * md.y; zp[14] += a * md.z; zp[15] += a * md.w;
            zp[16] += a * me.x; zp[17] += a * me.y; zp[18] += a * me.z; zp[19] += a * me.w;
        }
    }
}

__device__ __forceinline__ void load_rbf_lds(
    const float* cen, const float* lw, const float* rw, const float* linw,
    const float* Mt, const float* Cc,
    float4* sRbf, float* sLin, float* sMt, float* sC, int t)
{
    if (t < 64) {
        float s = expf(lw[t]) + 1e-6f;
        sRbf[t] = make_float4(cen[t], rw[t], -0.5f / (s * s), 0.0f);
    }
    if (t < 8)  sLin[t] = linw[t];
    if (t < 20) sC[t] = Cc[t];
    for (int i = t; i < 1280; i += 256) sMt[i] = Mt[i];
}

// ---------------- pass 2: z_pre + BN2 statistics ----------------
__global__ __launch_bounds__(256) void k_zpre_stats(
    const float* __restrict__ x, const float* __restrict__ cen,
    const float* __restrict__ lw, const float* __restrict__ rw,
    const float* __restrict__ linw, const float* __restrict__ Mt,
    const float* __restrict__ Cc, float* __restrict__ zout,
    float* __restrict__ stat2, int store)
{
    __shared__ __align__(16) float4 sRbf[64];
    __shared__ float sLin[8], sC[20];
    __shared__ __align__(16) float sMt[1280];
    __shared__ float sRed[4][8][40];

    const int t = threadIdx.x;
    load_rbf_lds(cen, lw, rw, linw, Mt, Cc, sRbf, sLin, sMt, sC, t);
    __syncthreads();

    const int row = blockIdx.x * 256 + t;
    float zp[20];
    zpre_row(x + (size_t)row * 64, sRbf, sLin, sMt, sC, zp);

    if (store) {
#pragma unroll
        for (int j = 0; j < 20; ++j) zout[(size_t)j * B_N + row] = zp[j];
    }

    float s_[20], q_[20];
#pragma unroll
    for (int j = 0; j < 20; ++j) { s_[j] = zp[j]; q_[j] = zp[j] * zp[j]; }
#pragma unroll
    for (int off = 32; off >= 8; off >>= 1) {
#pragma unroll
        for (int j = 0; j < 20; ++j) {
            s_[j] += __shfl_down(s_[j], off, 64);
            q_[j] += __shfl_down(q_[j], off, 64);
        }
    }
    const int wave = t >> 6, lane = t & 63;
    if (lane < 8) {
#pragma unroll
        for (int j = 0; j < 20; ++j) {
            sRed[wave][lane][j] = s_[j];
            sRed[wave][lane][20 + j] = q_[j];
        }
    }
    __syncthreads();
    if (t < 40) {
        float v = 0.0f;
#pragma unroll
        for (int w = 0; w < 4; ++w)
#pragma unroll
            for (int l = 0; l < 8; ++l) v += sRed[w][l][t];
        atomicAdd(&stat2[(blockIdx.x & 63) * 40 + t], v);
    }
}

__device__ __forceinline__ float gelu_exact(float v) {
    return 0.5f * v * (1.0f + erff(v * 0.70710678118654752440f));
}

__device__ __forceinline__ float fuzzy_head(
    const float z[20], const float4* sFz, const float* sHW, float hb)
{
    float acc = hb;
#pragma unroll 1
    for (int r = 0; r < 10; ++r) {
        float u = 0.0f, l = 0.0f;
#pragma unroll
        for (int j = 0; j < 20; ++j) {
            float4 p = sFz[r * 20 + j];   // (centre, nhu, nhl, _)
            float d = z[j] - p.x;
            float dd = d * d;
            u += __expf(dd * p.y);
            l += __expf(dd * p.z);
        }
        acc += sHW[r] * 0.025f * (u + l);   // 0.5 * mean(20) folded: /40
    }
    return acc;
}

// inline BN2 finalize from stat2 stripes
__device__ __forceinline__ void bn2_inline(
    const float* stat2, const float* g2, const float* b2,
    float* sT, float* sSc, float* sSh, int t)
{
    if (t < 40) {
        float s = 0.0f;
        for (int st = 0; st < 64; ++st) s += stat2[st * 40 + t];
        sT[t] = s;
    }
    __syncthreads();
    if (t < 20) {
        float mu = sT[t] * (1.0f / B_N);
        float var = sT[20 + t] * (1.0f / B_N) - mu * mu;
        float sc = g2[t] * rsqrtf(var + 1e-5f);
        sSc[t] = sc;
        sSh[t] = b2[t] - mu * sc;
    }
}

// ---------------- pass 3 (variant A): load z_pre from ws ----------------
__global__ __launch_bounds__(256) void k_out_load(
    const float* __restrict__ zin, const float* __restrict__ stat2,
    const float* __restrict__ g2, const float* __restrict__ b2,
    const float* __restrict__ nh, const float* __restrict__ fzc,
    const float* __restrict__ hW, const float* __restrict__ hb,
    float* __restrict__ out)
{
    __shared__ float sT[40], sSc[20], sSh[20], sHW[10];
    __shared__ __align__(16) float4 sFz[200];
    const int t = threadIdx.x;
    if (t < 10) sHW[t] = hW[t];
    for (int i = t; i < 200; i += 256)
        sFz[i] = make_float4(fzc[i], nh[i], nh[200 + i], 0.0f);
    bn2_inline(stat2, g2, b2, sT, sSc, sSh, t);
    __syncthreads();

    const int row = blockIdx.x * 256 + t;
    float z[20];
#pragma unroll
    for (int j = 0; j < 20; ++j) {
        float zp = zin[(size_t)j * B_N + row];
        z[j] = gelu_exact(sSc[j] * zp + sSh[j]);
    }
    out[row] = fuzzy_head(z, sFz, sHW, hb[0]);
}

// ---------------- pass 3 (variant B): recompute z_pre from x ----------------
__global__ __launch_bounds__(256) void k_out_rec(
    const float* __restrict__ x, const float* __restrict__ cen,
    const float* __restrict__ lw, const float* __restrict__ rw,
    const float* __restrict__ linw, const float* __restrict__ Mt,
    const float* __restrict__ Cc, const float* __restrict__ stat2,
    const float* __restrict__ g2, const float* __restrict__ b2,
    const float* __restrict__ nh, const float* __restrict__ fzc,
    const float* __restrict__ hW, const float* __restrict__ hb,
    float* __restrict__ out)
{
    __shared__ __align__(16) float4 sRbf[64];
    __shared__ float sLin[8], sC[20];
    __shared__ __align__(16) float sMt[1280];
    __shared__ float sT[40], sSc[20], sSh[20], sHW[10];
    __shared__ __align__(16) float4 sFz[200];

    const int t = threadIdx.x;
    load_rbf_lds(cen, lw, rw, linw, Mt, Cc, sRbf, sLin, sMt, sC, t);
    if (t < 10) sHW[t] = hW[t];
    for (int i = t; i < 200; i += 256)
        sFz[i] = make_float4(fzc[i], nh[i], nh[200 + i], 0.0f);
    bn2_inline(stat2, g2, b2, sT, sSc, sSh, t);
    __syncthreads();

    const int row = blockIdx.x * 256 + t;
    float zp[20];
    zpre_row(x + (size_t)row * 64, sRbf, sLin, sMt, sC, zp);
    float z[20];
#pragma unroll
    for (int j = 0; j < 20; ++j)
        z[j] = gelu_exact(sSc[j] * zp[j] + sSh[j]);
    out[row] = fuzzy_head(z, sFz, sHW, hb[0]);
}

// ---------------- launcher ----------------
extern "C" void kernel_launch(void* const* d_in, const int* in_sizes, int n_in,
                              void* d_out, int out_size, void* d_ws, size_t ws_size,
                              hipStream_t stream) {
    const float* x    = (const float*)d_in[0];
    const float* cen  = (const float*)d_in[1];
    const float* lw   = (const float*)d_in[2];
    const float* rw   = (const float*)d_in[3];
    const float* linw = (const float*)d_in[4];
    const float* Wp   = (const float*)d_in[5];
    const float* pb   = (const float*)d_in[6];
    const float* g1   = (const float*)d_in[7];
    const float* b1   = (const float*)d_in[8];
    const float* fpW  = (const float*)d_in[9];
    const float* fpb  = (const float*)d_in[10];
    const float* g2   = (const float*)d_in[11];
    const float* b2   = (const float*)d_in[12];
    const float* fzc  = (const float*)d_in[13];
    const float* lsu  = (const float*)d_in[14];
    const float* lsl  = (const float*)d_in[15];
    const float* hW   = (const float*)d_in[16];
    const float* hb   = (const float*)d_in[17];

    float* ws    = (float*)d_ws;
    float* stat1 = ws + WS_STAT1;
    float* Mt    = ws + WS_MT;
    float* Cc    = ws + WS_C;
    float* stat2 = ws + WS_STAT2;
    float* nh    = ws + WS_NH;
    float* zbuf  = ws + WS_Z;
    float* outp  = (float*)d_out;

    const size_t need = ((size_t)WS_Z + (size_t)20 * B_N) * sizeof(float);
    const int store = (ws_size >= need) ? 1 : 0;

    hipMemsetAsync(stat1, 0, (size_t)ST1_SZ * sizeof(float), stream);
    k_act_moments<<<1024, 256, 0, stream>>>(x, cen, lw, rw, linw, stat1);
    k_build<<<1, 256, 0, stream>>>(stat1, fpW, fpb, g1, b1, Wp, pb, lsu, lsl,
                                   Mt, Cc, nh, stat2);
    k_zpre_stats<<<512, 256, 0, stream>>>(x, cen, lw, rw, linw, Mt, Cc,
                                          store ? zbuf : nullptr, stat2, store);
    if (store) {
        k_out_load<<<512, 256, 0, stream>>>(zbuf, stat2, g2, b2, nh, fzc, hW, hb, outp);
    } else {
        k_out_rec<<<512, 256, 0, stream>>>(x, cen, lw, rw, linw, Mt, Cc,
                                           stat2, g2, b2, nh, fzc, hW, hb, outp);
    }
}